// Round 5
// baseline (477.570 us; speedup 1.0000x reference)
//
#include <hip/hip_runtime.h>

// MirrorAttention on MI355X (gfx950). Round 9: fix proj4's 16-way LDS bank
// conflicts (2.0e7/dispatch) + 2x fp32 overfetch (141MB vs 74MB ideal):
//   - castT_kernel: x fp32 [C][N] -> bf16 xT [N][C] once per tensor.
//     Conflict-light: packs 2 adjacent c into u32 (2-way max, free), vector IO.
//   - projb_kernel: all projections read bf16 xT with the VERIFIED scoreT
//     staging (both operands row-major short8 -> ds_write_b128, conflict-free)
//     and the VERIFIED proj4 epilogue. Numerics identical to R8.
//   - xT slots live inside the PT region (dead at cast/proj time); ws stays
//     114,112,512 B (same as R8 PASS).
//   - scoreT / pv2 / final / transpose / fold / fallback: byte-for-byte R8.

typedef __attribute__((ext_vector_type(8))) short short8;
typedef __attribute__((ext_vector_type(4))) short short4_t;
typedef __attribute__((ext_vector_type(8))) __bf16 bf16x8;
typedef __attribute__((ext_vector_type(4))) float f32x4;

#define DEV __device__ __forceinline__

constexpr int BB = 8, CC = 512, MID = 128, NB = 2304;
constexpr float ATT_SCALE = 0.08838834764831845f;   // 128^-0.5
constexpr float RSQ = 0.9999950000374998f;          // 1/sqrt(1+1e-5)

DEV float bf2f(unsigned short u) {
    unsigned int x = ((unsigned int)u) << 16;
    return __builtin_bit_cast(float, x);
}
DEV unsigned short f2bf(float f) {   // round-to-nearest-even
    unsigned int x = __builtin_bit_cast(unsigned int, f);
    x += 0x7fffu + ((x >> 16) & 1u);
    return (unsigned short)(x >> 16);
}
DEV bf16x8 ldfrag(const unsigned short* p) {
    return __builtin_bit_cast(bf16x8, *(const short8*)p);
}

// ---------------------------------------------------------------------------
// fold kernel (R8 verbatim)
__global__ __launch_bounds__(256)
void fold_kernel(const float* __restrict__ Wa, const float* __restrict__ ba,
                 const float* __restrict__ ga, const float* __restrict__ ta,
                 const float* __restrict__ Wv, const float* __restrict__ bv,
                 const float* __restrict__ gv, const float* __restrict__ tv,
                 const float* __restrict__ Wgav, const float* __restrict__ bgav,
                 const float* __restrict__ Wgah, const float* __restrict__ bgah,
                 const float* __restrict__ Wfav, const float* __restrict__ bfav,
                 const float* __restrict__ Wfah, const float* __restrict__ bfah,
                 unsigned short* __restrict__ WaE, unsigned short* __restrict__ WvE,
                 unsigned short* __restrict__ WgavE, unsigned short* __restrict__ WgahE,
                 unsigned short* __restrict__ WfavE, unsigned short* __restrict__ WfahE,
                 float* __restrict__ biases)
{
    int idx = blockIdx.x * 256 + threadIdx.x;
    if (idx < 65536) {
        int m = idx >> 9;                  // row of [128][512]
        WaE[idx]   = f2bf(ga[m] * RSQ * Wa[idx]);
        WvE[idx]   = f2bf(gv[m] * RSQ * Wv[idx]);
        WgavE[idx] = f2bf(Wgav[idx]);
        WgahE[idx] = f2bf(Wgah[idx]);
        WfavE[idx] = f2bf(Wfav[idx]);      // [512][128] flat
        WfahE[idx] = f2bf(Wfah[idx]);
    }
    if (idx < 128) {
        biases[idx]       = ba[idx] * ga[idx] * RSQ + ta[idx];
        biases[128 + idx] = bv[idx] * gv[idx] * RSQ + tv[idx];
        biases[256 + idx] = bgav[idx];
        biases[384 + idx] = bgah[idx];
    }
    if (idx < 512) {
        biases[512 + idx]  = bfav[idx];
        biases[1024 + idx] = bfah[idx];
    }
}

// ---------------------------------------------------------------------------
// Generic MFMA GEMM (R8 verbatim; big path uses <false,3,true,true,false> for
// the finals; fallback uses all variants).
template<bool AT, int EPI, bool BF32, bool OF32, bool EXPB>
__global__ __launch_bounds__(256)
void gemm_kernel(const unsigned short* __restrict__ A, long sAb,
                 const void* __restrict__ Bm, long sBb,
                 void* __restrict__ Out, long sOb,
                 const float* __restrict__ bias,
                 const float* __restrict__ resid, long sRb,
                 const float* __restrict__ stats,
                 int Mdim, int Kdim, int Ndim, float outscale)
{
    constexpr int TM = 64, TN = 64, TK = 32, LD = TK + 8;
    __shared__ unsigned short As[TM * LD];
    __shared__ unsigned short Bs[TN * LD];

    const int tid  = threadIdx.x;
    const int lane = tid & 63;
    const int wave = tid >> 6;
    const int wm = wave >> 1, wn = wave & 1;
    const int m0 = blockIdx.y * TM, n0 = blockIdx.x * TN;
    const int z  = blockIdx.z;

    const unsigned short* Ab = A + (long)z * sAb;

    f32x4 acc[2][2] = {};

    const int ar = tid >> 2, ac = (tid & 3) * 8;   // row-major A staging
    const int tk = tid >> 3, tq = (tid & 7) * 8;   // K-major (transpose) staging
    const int lm = lane & 15, kq = (lane >> 4) * 8;

    for (int k0 = 0; k0 < Kdim; k0 += TK) {
        if constexpr (!AT) {
            short8 v = *(const short8*)(Ab + (long)(m0 + ar) * Kdim + (k0 + ac));
            *(short8*)(&As[ar * LD + ac]) = v;
        } else {
            short8 v = *(const short8*)(Ab + (long)(k0 + tk) * Mdim + (m0 + tq));
            #pragma unroll
            for (int i = 0; i < 8; i++) As[(tq + i) * LD + tk] = (unsigned short)v[i];
        }
        if constexpr (BF32) {
            const float* Bf = (const float*)Bm + (long)z * sBb;
            f32x4 a0 = *(const f32x4*)(Bf + (long)(k0 + tk) * Ndim + (n0 + tq));
            f32x4 a1 = *(const f32x4*)(Bf + (long)(k0 + tk) * Ndim + (n0 + tq) + 4);
            #pragma unroll
            for (int i = 0; i < 4; i++) Bs[(tq + i) * LD + tk]     = f2bf(a0[i]);
            #pragma unroll
            for (int i = 0; i < 4; i++) Bs[(tq + 4 + i) * LD + tk] = f2bf(a1[i]);
        } else {
            const unsigned short* Bu = (const unsigned short*)Bm + (long)z * sBb;
            short8 v = *(const short8*)(Bu + (long)(k0 + tk) * Ndim + (n0 + tq));
            if constexpr (EXPB) {
                const long krow = (long)z * NB + (k0 + tk);
                const float mrow = stats[2 * krow];
                const float rinv = stats[2 * krow + 1];
                #pragma unroll
                for (int i = 0; i < 8; i++)
                    Bs[(tq + i) * LD + tk] =
                        f2bf(__expf(bf2f((unsigned short)v[i]) - mrow) * rinv);
            } else {
                #pragma unroll
                for (int i = 0; i < 8; i++) Bs[(tq + i) * LD + tk] = (unsigned short)v[i];
            }
        }
        __syncthreads();

        bf16x8 afr[2], bfr[2];
        afr[0] = __builtin_bit_cast(bf16x8, *(const short8*)(&As[(wm * 32 + lm) * LD + kq]));
        afr[1] = __builtin_bit_cast(bf16x8, *(const short8*)(&As[(wm * 32 + 16 + lm) * LD + kq]));
        bfr[0] = __builtin_bit_cast(bf16x8, *(const short8*)(&Bs[(wn * 32 + lm) * LD + kq]));
        bfr[1] = __builtin_bit_cast(bf16x8, *(const short8*)(&Bs[(wn * 32 + 16 + lm) * LD + kq]));
        #pragma unroll
        for (int i = 0; i < 2; i++)
            #pragma unroll
            for (int j = 0; j < 2; j++)
                acc[i][j] = __builtin_amdgcn_mfma_f32_16x16x32_bf16(afr[i], bfr[j], acc[i][j], 0, 0, 0);
        __syncthreads();
    }

    const float* Rb = nullptr;
    if constexpr (EPI == 3) Rb = resid + (long)z * sRb;

    const int col = lane & 15, rb = (lane >> 4) * 4;
    #pragma unroll
    for (int i = 0; i < 2; i++) {
        #pragma unroll
        for (int j = 0; j < 2; j++) {
            const int mB = m0 + wm * 32 + i * 16 + rb;
            const int on = n0 + wn * 32 + j * 16 + col;
            #pragma unroll
            for (int r = 0; r < 4; r++) {
                const int m = mB + r;
                float v = acc[i][j][r];
                if constexpr (EPI == 0) {
                    v *= outscale;
                } else {
                    v += bias[m];
                    if constexpr (EPI == 1) v = fmaxf(v, 0.0f);
                    if constexpr (EPI == 3) v += Rb[(long)m * Ndim + on];
                }
                if constexpr (OF32) {
                    float* Of = (float*)Out + (long)z * sOb;
                    Of[(long)m * Ndim + on] = v;
                } else {
                    unsigned short* Ou = (unsigned short*)Out + (long)z * sOb;
                    Ou[(long)m * Ndim + on] = f2bf(v);
                }
            }
        }
    }
}

// ---------------------------------------------------------------------------
// castT: src fp32 [CC][NB] -> dst bf16 [NB][CC], per batch. grid (36, 8, 8).
// LDS holds u32 pairs (2 adjacent c per u32) with LD=33 pad: all LDS ops are
// <=2-way bank aliased (free). Global loads f32x4 coalesced; stores short8.
__global__ __launch_bounds__(256)
void castT_kernel(const float* __restrict__ src, unsigned short* __restrict__ dst)
{
    const long sX = (long)CC * NB;
    const int b = blockIdx.z;
    const float* s = src + (long)b * sX;
    unsigned short* d = dst + (long)b * sX;
    const int n0 = blockIdx.x * 64, c0 = blockIdx.y * 64;
    const int t = threadIdx.x;

    __shared__ unsigned int T32[64 * 33];   // [n local][c pair], pad 33

    #pragma unroll
    for (int r = 0; r < 2; r++) {
        const int cp = (t >> 4) + 16 * r;        // 0..31
        const int nb = (t & 15) * 4;             // 0..60
        const int c  = c0 + 2 * cp;
        f32x4 v0 = *(const f32x4*)(s + (long)c * NB + n0 + nb);
        f32x4 v1 = *(const f32x4*)(s + (long)(c + 1) * NB + n0 + nb);
        #pragma unroll
        for (int i = 0; i < 4; i++) {
            unsigned int u = (unsigned int)f2bf(v0[i]) |
                             ((unsigned int)f2bf(v1[i]) << 16);
            T32[(nb + i) * 33 + cp] = u;
        }
    }
    __syncthreads();
    #pragma unroll
    for (int rr = 0; rr < 2; rr++) {
        const int nr = (t >> 3) + 32 * rr;       // 0..63
        const int mc = (t & 7) * 8;              // shorts, 0..56
        unsigned int q[4];
        #pragma unroll
        for (int j = 0; j < 4; j++) q[j] = T32[nr * 33 + (mc >> 1) + j];
        short8 w;
        #pragma unroll
        for (int j = 0; j < 4; j++) {
            w[2 * j]     = (short)(q[j] & 0xffffu);
            w[2 * j + 1] = (short)(q[j] >> 16);
        }
        *(short8*)(d + (long)(n0 + nr) * CC + c0 + mc) = w;
    }
}

// ---------------------------------------------------------------------------
// projb: 1x1 projections from bf16 xT [N][CC]. Both operands staged row-major
// vectorized (verified scoreT pattern); epilogue = verified proj4 epilogue
// (natural [MID][NB] out, bias + optional relu). grid (36, 2, 8*ncls).
__global__ __launch_bounds__(256)
void projb_kernel(const unsigned short* __restrict__ W0, const unsigned short* __restrict__ W1,
                  const unsigned short* __restrict__ W2, const unsigned short* __restrict__ W3,
                  const float* __restrict__ b0, const float* __restrict__ b1,
                  const float* __restrict__ b2, const float* __restrict__ b3,
                  const unsigned short* __restrict__ X0, const unsigned short* __restrict__ X1,
                  const unsigned short* __restrict__ X2, const unsigned short* __restrict__ X3,
                  unsigned short* __restrict__ D0, unsigned short* __restrict__ D1,
                  unsigned short* __restrict__ D2, unsigned short* __restrict__ D3,
                  int reluMask)
{
    constexpr int TK = 32, LD = TK + 8;
    const long sF = (long)MID * NB, sX = (long)CC * NB;
    const int zz = blockIdx.z, cls = zz >> 3, b = zz & 7;
    const unsigned short* W = cls == 0 ? W0 : cls == 1 ? W1 : cls == 2 ? W2 : W3;
    const float* bi = cls == 0 ? b0 : cls == 1 ? b1 : cls == 2 ? b2 : b3;
    const unsigned short* Xt = (cls == 0 ? X0 : cls == 1 ? X1 : cls == 2 ? X2 : X3) + (long)b * sX;
    unsigned short* outp = (cls == 0 ? D0 : cls == 1 ? D1 : cls == 2 ? D2 : D3) + (long)b * sF;
    const bool relu = (reluMask >> cls) & 1;

    __shared__ unsigned short As[64 * LD];
    __shared__ unsigned short Bs[64 * LD];

    const int tid = threadIdx.x, lane = tid & 63, wave = tid >> 6;
    const int wm = wave >> 1, wn = wave & 1;
    const int m0 = blockIdx.y * 64, n0 = blockIdx.x * 64;
    const int ar = tid >> 2, ac = (tid & 3) * 8;
    const int lm = lane & 15, kq = (lane >> 4) * 8;

    f32x4 acc[2][2] = {};
    for (int k0 = 0; k0 < CC; k0 += TK) {
        *(short8*)(&As[ar * LD + ac]) = *(const short8*)(W  + (long)(m0 + ar) * CC + (k0 + ac));
        *(short8*)(&Bs[ar * LD + ac]) = *(const short8*)(Xt + (long)(n0 + ar) * CC + (k0 + ac));
        __syncthreads();
        bf16x8 afr[2], bfr[2];
        afr[0] = ldfrag(&As[(wm * 32 + lm) * LD + kq]);
        afr[1] = ldfrag(&As[(wm * 32 + 16 + lm) * LD + kq]);
        bfr[0] = ldfrag(&Bs[(wn * 32 + lm) * LD + kq]);
        bfr[1] = ldfrag(&Bs[(wn * 32 + 16 + lm) * LD + kq]);
        #pragma unroll
        for (int i = 0; i < 2; i++)
            #pragma unroll
            for (int j = 0; j < 2; j++)
                acc[i][j] = __builtin_amdgcn_mfma_f32_16x16x32_bf16(afr[i], bfr[j], acc[i][j], 0, 0, 0);
        __syncthreads();
    }

    const int col = lane & 15, rb = (lane >> 4) * 4;
    #pragma unroll
    for (int i = 0; i < 2; i++) {
        #pragma unroll
        for (int j = 0; j < 2; j++) {
            const int mB = m0 + wm * 32 + i * 16 + rb;
            const int on = n0 + wn * 32 + j * 16 + col;
            #pragma unroll
            for (int r = 0; r < 4; r++) {
                const int m = mB + r;
                float v = acc[i][j][r] + bi[m];
                if (relu) v = fmaxf(v, 0.0f);
                outp[(long)m * NB + on] = f2bf(v);
            }
        }
    }
}

// ---------------------------------------------------------------------------
// transpose_kernel (R8 verbatim): src [128][NB] bf16 -> dst [NB][128].
__global__ __launch_bounds__(256)
void transpose_kernel(const unsigned short* __restrict__ src,
                      unsigned short* __restrict__ dst)
{
    constexpr int LT = 72;
    const long sF = (long)MID * NB;
    const int b = blockIdx.z;
    const unsigned short* s = src + (long)b * sF;
    unsigned short* d = dst + (long)b * sF;
    const int n0 = blockIdx.x * 64, m0 = blockIdx.y * 64;
    const int tid = threadIdx.x;
    const int tk = tid >> 3, tq = (tid & 7) * 8;

    __shared__ unsigned short T[64 * LT];

    #pragma unroll
    for (int mm = 0; mm < 64; mm += 32) {
        short8 v = *(const short8*)(s + (long)(m0 + mm + tk) * NB + n0 + tq);
        #pragma unroll
        for (int e = 0; e < 8; e++) T[(tq + e) * LT + mm + tk] = (unsigned short)v[e];
    }
    __syncthreads();
    #pragma unroll
    for (int rr = 0; rr < 2; rr++) {
        int c = rr * 256 + tid;
        int nr = c >> 3, mc = (c & 7) * 8;
        *(short8*)(d + (long)(n0 + nr) * MID + m0 + mc) = *(const short8*)(&T[nr * LT + mc]);
    }
}

// ---------------------------------------------------------------------------
// scoreT (R8 verbatim): PT[key m][query n] + fused per-query exp-sums.
__global__ __launch_bounds__(256)
void scoreT_kernel(const unsigned short* __restrict__ faT,
                   const unsigned short* __restrict__ fqT,
                   unsigned short* __restrict__ PT,
                   float* __restrict__ sums)
{
    constexpr int LD = 40;
    const long sF = (long)MID * NB, sP = (long)NB * NB;
    const int z = blockIdx.z;
    const unsigned short* Ab = faT + (long)z * sF;
    const unsigned short* Bb = fqT + (long)z * sF;
    unsigned short* Ou = PT + (long)z * sP;
    float* sm = sums + (long)z * NB;

    __shared__ unsigned short As[64 * LD];
    __shared__ unsigned short Bs[64 * LD];

    const int tid = threadIdx.x, lane = tid & 63, wave = tid >> 6;
    const int wm = wave >> 1, wn = wave & 1;
    const int m0 = blockIdx.y * 64, n0 = blockIdx.x * 64;
    const int ar = tid >> 2, ac = (tid & 3) * 8;
    const int lm = lane & 15, kq = (lane >> 4) * 8;

    f32x4 acc[2][2] = {};
    #pragma unroll
    for (int k0 = 0; k0 < MID; k0 += 32) {
        *(short8*)(&As[ar * LD + ac]) = *(const short8*)(Ab + (long)(m0 + ar) * MID + (k0 + ac));
        *(short8*)(&Bs[ar * LD + ac]) = *(const short8*)(Bb + (long)(n0 + ar) * MID + (k0 + ac));
        __syncthreads();
        bf16x8 afr[2], bfr[2];
        afr[0] = ldfrag(&As[(wm * 32 + lm) * LD + kq]);
        afr[1] = ldfrag(&As[(wm * 32 + 16 + lm) * LD + kq]);
        bfr[0] = ldfrag(&Bs[(wn * 32 + lm) * LD + kq]);
        bfr[1] = ldfrag(&Bs[(wn * 32 + 16 + lm) * LD + kq]);
        #pragma unroll
        for (int i = 0; i < 2; i++)
            #pragma unroll
            for (int j = 0; j < 2; j++)
                acc[i][j] = __builtin_amdgcn_mfma_f32_16x16x32_bf16(afr[i], bfr[j], acc[i][j], 0, 0, 0);
        __syncthreads();
    }

    const int col = lane & 15, rb = (lane >> 4) * 4;
    float csum[2] = {0.f, 0.f};
    #pragma unroll
    for (int i = 0; i < 2; i++) {
        #pragma unroll
        for (int j = 0; j < 2; j++) {
            const int mB = m0 + wm * 32 + i * 16 + rb;
            const int on = n0 + wn * 32 + j * 16 + col;
            #pragma unroll
            for (int r = 0; r < 4; r++) {
                unsigned short u = f2bf(acc[i][j][r] * ATT_SCALE);
                Ou[(long)(mB + r) * NB + on] = u;
                csum[j] += __expf(bf2f(u));
            }
        }
    }
    csum[0] += __shfl_xor(csum[0], 16, 64);
    csum[0] += __shfl_xor(csum[0], 32, 64);
    csum[1] += __shfl_xor(csum[1], 16, 64);
    csum[1] += __shfl_xor(csum[1], 32, 64);
    if (lane < 16) {
        atomicAdd(&sm[n0 + wn * 32 + lane],      csum[0]);
        atomicAdd(&sm[n0 + wn * 32 + 16 + lane], csum[1]);
    }
}

// ---------------------------------------------------------------------------
// stats_inv (R8 verbatim)
__global__ __launch_bounds__(256)
void stats_inv_kernel(float* __restrict__ p)
{
    int idx = blockIdx.x * 256 + threadIdx.x;
    if (idx < BB * NB) p[idx] = 1.0f / p[idx];
}

// ---------------------------------------------------------------------------
// pv2 (R8 verbatim): omidF += g * (exp(PT)*rinv), split-K=3, fp32 atomicAdd.
__global__ __launch_bounds__(256)
void pv2_kernel(const unsigned short* __restrict__ g,
                const unsigned short* __restrict__ PT,
                const float* __restrict__ rinv,
                float* __restrict__ omidF)
{
    constexpr int TK = 32, LD = TK + 8;
    const long sF = (long)MID * NB, sP = (long)NB * NB;
    const int zb = blockIdx.z / 3, zs = blockIdx.z % 3;
    const unsigned short* Ab = g + (long)zb * sF;
    const unsigned short* Bt = PT + (long)zb * sP;
    const float* rv = rinv + (long)zb * NB;
    float* Of = omidF + (long)zb * sF;

    __shared__ unsigned short As[64 * LD];
    __shared__ unsigned short Bs[64 * LD];

    const int tid = threadIdx.x, lane = tid & 63, wave = tid >> 6;
    const int wm = wave >> 1, wn = wave & 1;
    const int m0 = blockIdx.y * 64, n0 = blockIdx.x * 64;
    const int ar = tid >> 2, ac = (tid & 3) * 8;
    const int lm = lane & 15, kq = (lane >> 4) * 8;

    f32x4 acc[2][2] = {};
    const int kBeg = zs * 768, kEnd = kBeg + 768;
    for (int k0 = kBeg; k0 < kEnd; k0 += TK) {
        *(short8*)(&As[ar * LD + ac]) = *(const short8*)(Ab + (long)(m0 + ar) * NB + (k0 + ac));
        {
            short8 v = *(const short8*)(Bt + (long)(n0 + ar) * NB + (k0 + ac));
            f32x4 r0 = *(const f32x4*)(rv + k0 + ac);
            f32x4 r1 = *(const f32x4*)(rv + k0 + ac + 4);
            short8 w;
            #pragma unroll
            for (int e = 0; e < 4; e++)
                w[e] = (short)f2bf(__expf(bf2f((unsigned short)v[e])) * r0[e]);
            #pragma unroll
            for (int e = 0; e < 4; e++)
                w[4 + e] = (short)f2bf(__expf(bf2f((unsigned short)v[4 + e])) * r1[e]);
            *(short8*)(&Bs[ar * LD + ac]) = w;
        }
        __syncthreads();

        bf16x8 afr[2], bfr[2];
        afr[0] = ldfrag(&As[(wm * 32 + lm) * LD + kq]);
        afr[1] = ldfrag(&As[(wm * 32 + 16 + lm) * LD + kq]);
        bfr[0] = ldfrag(&Bs[(wn * 32 + lm) * LD + kq]);
        bfr[1] = ldfrag(&Bs[(wn * 32 + 16 + lm) * LD + kq]);
        #pragma unroll
        for (int i = 0; i < 2; i++)
            #pragma unroll
            for (int j = 0; j < 2; j++)
                acc[i][j] = __builtin_amdgcn_mfma_f32_16x16x32_bf16(afr[i], bfr[j], acc[i][j], 0, 0, 0);
        __syncthreads();
    }

    const int col = lane & 15, rb = (lane >> 4) * 4;
    #pragma unroll
    for (int i = 0; i < 2; i++)
        #pragma unroll
        for (int j = 0; j < 2; j++) {
            const int mB = m0 + wm * 32 + i * 16 + rb;
            const int on = n0 + wn * 32 + j * 16 + col;
            #pragma unroll
            for (int r = 0; r < 4; r++)
                atomicAdd(&Of[(long)(mB + r) * NB + on], acc[i][j][r]);
        }
}

// ---------------------------------------------------------------------------
// zerof (R8 verbatim)
__global__ __launch_bounds__(256)
void zerof_kernel(float* __restrict__ p, int n)
{
    int stride = gridDim.x * 256;
    for (int i = blockIdx.x * 256 + threadIdx.x; i < n; i += stride) p[i] = 0.0f;
}

// ---------------------------------------------------------------------------
// softmax_rows (fallback only, R8 verbatim)
__global__ __launch_bounds__(256)
void softmax_rows(unsigned short* __restrict__ P)
{
    const int row  = blockIdx.x * 4 + (threadIdx.x >> 6);
    const int lane = threadIdx.x & 63;
    unsigned short* p = P + (long)row * NB;

    float vals[36];
    #pragma unroll
    for (int c = 0; c < 4; c++) {
        short8 v = *(const short8*)(p + c * 512 + lane * 8);
        #pragma unroll
        for (int e = 0; e < 8; e++) vals[c * 8 + e] = bf2f((unsigned short)v[e]);
    }
    {
        short4_t v = *(const short4_t*)(p + 2048 + lane * 4);
        #pragma unroll
        for (int e = 0; e < 4; e++) vals[32 + e] = bf2f((unsigned short)v[e]);
    }

    float mx = vals[0];
    #pragma unroll
    for (int i = 1; i < 36; i++) mx = fmaxf(mx, vals[i]);
    #pragma unroll
    for (int off = 32; off > 0; off >>= 1) mx = fmaxf(mx, __shfl_xor(mx, off, 64));

    float s = 0.f;
    #pragma unroll
    for (int i = 0; i < 36; i++) { vals[i] = __expf(vals[i] - mx); s += vals[i]; }
    #pragma unroll
    for (int off = 32; off > 0; off >>= 1) s += __shfl_xor(s, off, 64);
    const float rs = 1.0f / s;

    #pragma unroll
    for (int c = 0; c < 4; c++) {
        short8 w;
        #pragma unroll
        for (int e = 0; e < 8; e++) w[e] = (short)f2bf(vals[c * 8 + e] * rs);
        *(short8*)(p + c * 512 + lane * 8) = w;
    }
    {
        short4_t w;
        #pragma unroll
        for (int e = 0; e < 4; e++) w[e] = (short)f2bf(vals[32 + e] * rs);
        *(short4_t*)(p + 2048 + lane * 4) = w;
    }
}

// ---------------------------------------------------------------------------
extern "C" void kernel_launch(void* const* d_in, const int* in_sizes, int n_in,
                              void* d_out, int out_size, void* d_ws, size_t ws_size,
                              hipStream_t stream)
{
    const float* x    = (const float*)d_in[0];
    const float* x_h  = (const float*)d_in[1];
    const float* x_v  = (const float*)d_in[2];
    const float* Wa   = (const float*)d_in[3];
    const float* ba   = (const float*)d_in[4];
    const float* ga   = (const float*)d_in[5];
    const float* ta   = (const float*)d_in[6];
    const float* Wv   = (const float*)d_in[7];
    const float* bv   = (const float*)d_in[8];
    const float* gv   = (const float*)d_in[9];
    const float* tv   = (const float*)d_in[10];
    const float* Wgav = (const float*)d_in[11];
    const float* bgav = (const float*)d_in[12];
    const float* Wgah = (const float*)d_in[13];
    const float* bgah = (const float*)d_in[14];
    const float* Wfav = (const float*)d_in[15];
    const float* bfav = (const float*)d_in[16];
    const float* Wfah = (const float*)d_in[17];
    const float* bfah = (const float*)d_in[18];
    float* out = (float*)d_out;

    const long sX = (long)CC * NB;        // 1179648
    const long sF = (long)MID * NB;       // 294912
    const long sP = (long)NB * NB;        // 5308416
    const long HALF = (long)BB * sX;

    const dim3 blk(256);
    unsigned short* ws = (unsigned short*)d_ws;

    // ---- big-path ws layout (shorts), total 57,056,256 shorts = 114,112,512 B
    //  0        WaE..WfahE (6 x 65536)               -> 393216
    //  393216   biases f32 (1536)                    -> 396288
    //  396288   rinv f32 (8*2304 = 18432 f)          -> 433152
    //  433152   fa                                   -> 2792448 } omidF f32
    //  2792448  fv                                   -> 5151744 } overlay
    //  5151744  faT                                  -> 7511040
    //  7511040  gav (later: fh)                      -> 9870336
    //  9870336  gah                                  -> 12229632
    //  12229632 fqT                                  -> 14588928
    //  14588928 PT (8*5308416)                       -> 57056256
    //           [xT slotA = PT+0, slotB = PT+9437184 — dead before scoreT]
    constexpr size_t WS_BIG = 114112512ull;

    if (ws_size >= WS_BIG) {
        unsigned short* WaE   = ws;
        unsigned short* WvE   = ws + 65536;
        unsigned short* WgavE = ws + 131072;
        unsigned short* WgahE = ws + 196608;
        unsigned short* WfavE = ws + 262144;
        unsigned short* WfahE = ws + 327680;
        float* biases = (float*)(ws + 393216);
        float* rinv   = (float*)(ws + 396288);
        unsigned short* fa   = ws + 433152;
        unsigned short* fv   = ws + 2792448;
        float* omidF         = (float*)(ws + 433152);    // overlays fa+fv
        unsigned short* faT  = ws + 5151744;
        unsigned short* gav  = ws + 7511040;             // later holds fh
        unsigned short* gah  = ws + 9870336;
        unsigned short* fqT  = ws + 12229632;
        unsigned short* PT   = ws + 14588928;
        unsigned short* slotA = PT;                      // xT(x), later xT(x_h)
        unsigned short* slotB = PT + 9437184;            // xT(x_v)

        float* baE   = biases;
        float* bvE   = biases + 128;
        float* bgavF = biases + 256;
        float* bgahF = biases + 384;
        float* bfavF = biases + 512;
        float* bfahF = biases + 1024;

        fold_kernel<<<256, 256, 0, stream>>>(Wa, ba, ga, ta, Wv, bv, gv, tv,
                                             Wgav, bgav, Wgah, bgah, Wfav, bfav, Wfah, bfah,
                                             WaE, WvE, WgavE, WgahE, WfavE, WfahE, biases);

        castT_kernel<<<dim3(36, 8, 8), blk, 0, stream>>>(x,   slotA);
        castT_kernel<<<dim3(36, 8, 8), blk, 0, stream>>>(x_v, slotB);

        // cls 0=fa(relu, x) 1=fv(relu, x_v) 2=gav(x) 3=gah(x)
        projb_kernel<<<dim3(36, 2, 32), blk, 0, stream>>>(
            WaE, WvE, WgavE, WgahE,
            baE, bvE, bgavF, bgahF,
            slotA, slotB, slotA, slotA,
            fa, fv, gav, gah, 3);

        transpose_kernel<<<dim3(36, 2, 8), blk, 0, stream>>>(fa, faT);
        transpose_kernel<<<dim3(36, 2, 8), blk, 0, stream>>>(fv, fqT);

        // ---- direction v -> o_v at out+HALF ----
        zerof_kernel<<<72, blk, 0, stream>>>(rinv, BB * NB);
        scoreT_kernel<<<dim3(36, 36, 8), blk, 0, stream>>>(faT, fqT, PT, rinv);
        stats_inv_kernel<<<72, blk, 0, stream>>>(rinv);
        zerof_kernel<<<1024, blk, 0, stream>>>(omidF, (int)(BB * sF));  // fa/fv dead
        pv2_kernel<<<dim3(36, 2, 24), blk, 0, stream>>>(gav, PT, rinv, omidF);
        gemm_kernel<false,3,true,true,false><<<dim3(36,8,8), blk, 0, stream>>>(
            WfavE, 0, omidF, sF, out + HALF, sX, bfavF, x, sX, nullptr, CC, MID, NB, 1.f);

        // deferred fh: PT(v) dead after pv2; gav dead after pv2
        castT_kernel<<<dim3(36, 8, 8), blk, 0, stream>>>(x_h, slotA);
        projb_kernel<<<dim3(36, 2, 8), blk, 0, stream>>>(
            WvE, WvE, WvE, WvE,
            bvE, bvE, bvE, bvE,
            slotA, slotA, slotA, slotA,
            gav, gav, gav, gav, 1);                      // fh -> gav region
        transpose_kernel<<<dim3(36, 2, 8), blk, 0, stream>>>(gav, fqT);

        // ---- direction h -> o_h at out[0] ----
        zerof_kernel<<<72, blk, 0, stream>>>(rinv, BB * NB);
        scoreT_kernel<<<dim3(36, 36, 8), blk, 0, stream>>>(faT, fqT, PT, rinv);
        stats_inv_kernel<<<72, blk, 0, stream>>>(rinv);
        zerof_kernel<<<1024, blk, 0, stream>>>(omidF, (int)(BB * sF));  // omidF v dead
        pv2_kernel<<<dim3(36, 2, 24), blk, 0, stream>>>(gah, PT, rinv, omidF);
        gemm_kernel<false,3,true,true,false><<<dim3(36,8,8), blk, 0, stream>>>(
            WfahE, 0, omidF, sF, out, sX, bfahF, x, sX, nullptr, CC, MID, NB, 1.f);

        return;
    }

    // ---------------- fallback: exact Round-3 per-batch path ----------------
    constexpr size_t WS_NEED = 7280640;
    if (ws_size < WS_NEED) return;

    unsigned short* WaE   = ws;
    unsigned short* WvE   = ws + 65536;
    unsigned short* WgavE = ws + 131072;
    unsigned short* WgahE = ws + 196608;
    unsigned short* WfavE = ws + 262144;
    unsigned short* WfahE = ws + 327680;
    float* biases = (float*)(ws + 393216);
    unsigned short* fab  = ws + 396288;
    unsigned short* qb   = ws + 691200;
    unsigned short* gb   = ws + 986112;
    unsigned short* omid = ws + 1281024;
    unsigned short* Pb = (unsigned short*)d_out;

    float* baE   = biases;
    float* bvE   = biases + 128;
    float* bgavF = biases + 256;
    float* bgahF = biases + 384;
    float* bfavF = biases + 512;
    float* bfahF = biases + 1024;

    fold_kernel<<<256, 256, 0, stream>>>(Wa, ba, ga, ta, Wv, bv, gv, tv,
                                         Wgav, bgav, Wgah, bgah, Wfav, bfav, Wfah, bfah,
                                         WaE, WvE, WgavE, WgahE, WfavE, WfahE, biases);

    for (int b = 0; b < BB; b++) {
        const float* xb  = x   + (long)b * sX;
        const float* xqb = x_v + (long)b * sX;
        gemm_kernel<false,1,true,false,false><<<dim3(36,2,1), blk, 0, stream>>>(WaE,   0, xb,  0, fab, 0, baE,   nullptr, 0, nullptr, MID, CC, NB, 1.f);
        gemm_kernel<false,1,true,false,false><<<dim3(36,2,1), blk, 0, stream>>>(WvE,   0, xqb, 0, qb,  0, bvE,   nullptr, 0, nullptr, MID, CC, NB, 1.f);
        gemm_kernel<false,2,true,false,false><<<dim3(36,2,1), blk, 0, stream>>>(WgavE, 0, xb,  0, gb,  0, bgavF, nullptr, 0, nullptr, MID, CC, NB, 1.f);
        gemm_kernel<true,0,false,false,false><<<dim3(36,36,1), blk, 0, stream>>>(qb, 0, fab, 0, Pb, 0, nullptr, nullptr, 0, nullptr, NB, MID, NB, ATT_SCALE);
        softmax_rows<<<NB / 4, blk, 0, stream>>>(Pb);
        gemm_kernel<false,0,false,false,false><<<dim3(36,2,1), blk, 0, stream>>>(gb, 0, Pb, 0, omid + (long)b * sF, 0, nullptr, nullptr, 0, nullptr, MID, NB, NB, 1.f);
    }
    gemm_kernel<false,3,false,true,false><<<dim3(36,8,8), blk, 0, stream>>>(WfavE, 0, omid, sF, out + HALF, sX, bfavF, x, sX, nullptr, CC, MID, NB, 1.f);

    for (int b = 0; b < BB; b++) {
        const float* xb  = x   + (long)b * sX;
        const float* xqb = x_h + (long)b * sX;
        gemm_kernel<false,1,true,false,false><<<dim3(36,2,1), blk, 0, stream>>>(WaE,   0, xb,  0, fab, 0, baE,   nullptr, 0, nullptr, MID, CC, NB, 1.f);
        gemm_kernel<false,1,true,false,false><<<dim3(36,2,1), blk, 0, stream>>>(WvE,   0, xqb, 0, qb,  0, bvE,   nullptr, 0, nullptr, MID, CC, NB, 1.f);
        gemm_kernel<false,2,true,false,false><<<dim3(36,2,1), blk, 0, stream>>>(WgahE, 0, xb,  0, gb,  0, bgahF, nullptr, 0, nullptr, MID, CC, NB, 1.f);
        gemm_kernel<true,0,false,false,false><<<dim3(36,36,1), blk, 0, stream>>>(qb, 0, fab, 0, Pb, 0, nullptr, nullptr, 0, nullptr, NB, MID, NB, ATT_SCALE);
        softmax_rows<<<NB / 4, blk, 0, stream>>>(Pb);
        gemm_kernel<false,0,false,false,false><<<dim3(36,2,1), blk, 0, stream>>>(gb, 0, Pb, 0, omid + (long)b * sF, 0, nullptr, nullptr, 0, nullptr, MID, NB, NB, 1.f);
    }
    gemm_kernel<false,3,false,true,false><<<dim3(36,8,8), blk, 0, stream>>>(WfahE, 0, omid, sF, out, sX, bfahF, x, sX, nullptr, CC, MID, NB, 1.f);

    (void)in_sizes; (void)n_in; (void)out_size;
}